// Round 5
// baseline (802.137 us; speedup 1.0000x reference)
//
#include <hip/hip_runtime.h>
#include <hip/hip_bf16.h>
#include <math.h>

typedef __bf16 bf16_t;
typedef __bf16 bf16x2_t __attribute__((ext_vector_type(2)));
typedef __bf16 bf16x4_t __attribute__((ext_vector_type(4)));
typedef __bf16 bf16x8_t __attribute__((ext_vector_type(8)));
typedef float f32x4_t __attribute__((ext_vector_type(4)));

#define B_N 1024
#define L_N 1024
#define T_N 32
#define H_N 2048
#define K_TOP 64
#define O_N 256
#define NCOL (T_N * H_N) /* 65536 */

// VGPR-budget rules on gfx950 (R1-R3 post-mortems):
//   __launch_bounds__(256, w) caps VGPRs at 256/w.
//   FULL UNROLL over a deep load loop (VMEM _or_ LDS) lets the compiler
//   batch loads arbitrarily deep -> pressure exceeds any cap -> scratch
//   spill (R1: 5GB, R2: 4.1GB, R3: 2.9GB phantom traffic). Fix is
//   structural: partial unroll + LDS-broadcast instead of literal-k shfl.

// ---------------- conversion: x -> bf16 ----------------
__global__ __launch_bounds__(256) void cvt_x_kernel(const float* __restrict__ x,
                                                    bf16_t* __restrict__ xb) {
  int i = (blockIdx.x * 256 + threadIdx.x) * 4;
  float4 v = *(const float4*)(x + i);
  bf16x4_t o;
  o[0] = (bf16_t)v.x; o[1] = (bf16_t)v.y; o[2] = (bf16_t)v.z; o[3] = (bf16_t)v.w;
  *(bf16x4_t*)(xb + i) = o;
}

// -------- conversion+transpose: Wt [T,L,H] f32 -> WT [T,H,L] bf16 --------
__global__ __launch_bounds__(256) void cvt_w_kernel(const float* __restrict__ W,
                                                    bf16_t* __restrict__ WT) {
  __shared__ float tile[64][65];
  int t = blockIdx.z;
  int h0 = blockIdx.x * 64;
  int l0 = blockIdx.y * 64;
  const float* src = W + (size_t)t * L_N * H_N;
  int hx = threadIdx.x & 63;
  int ly = threadIdx.x >> 6;
#pragma unroll
  for (int r = 0; r < 64; r += 4)
    tile[ly + r][hx] = src[(size_t)(l0 + ly + r) * H_N + h0 + hx];
  __syncthreads();
  bf16_t* dst = WT + (size_t)t * H_N * L_N;
  int lx = (threadIdx.x & 31) * 2;
  int hy = threadIdx.x >> 5;
#pragma unroll
  for (int r = 0; r < 64; r += 8) {
    int h = hy + r;
    bf16x2_t o;
    o[0] = (bf16_t)tile[lx][h];
    o[1] = (bf16_t)tile[lx + 1][h];
    *(bf16x2_t*)(dst + (size_t)(h0 + h) * L_N + l0 + lx) = o;
  }
}

// ---------------- GEMM1: hidden[b, t*2048+h] = sum_l x[b,l]*W[t,l,h] ----------------
#define BM 128
#define BN 128
#define BK 32

__device__ __forceinline__ void async_load16(const void* g, void* l) {
  __builtin_amdgcn_global_load_lds((const __attribute__((address_space(1))) void*)g,
                                   (__attribute__((address_space(3))) void*)l,
                                   16, 0, 0);
}

template <typename HT>
__global__ __launch_bounds__(256) void gemm1_kernel(const bf16_t* __restrict__ Xb,
                                                    const bf16_t* __restrict__ WT,
                                                    HT* __restrict__ hidden) {
  __shared__ bf16_t As[BM][BK]; // [m][k], row = 64 B
  __shared__ bf16_t Bs[BN][BK]; // [n][k], row = 64 B  (WT is already [n][k] in global)
  int tid = threadIdx.x;
  int wave = tid >> 6;
  int lane = tid & 63;
  int bid = blockIdx.x;

  // XCD-aware remap (dispatch model: XCD = bid % 8 round-robin).
  // R4 counters: FETCH 530 MB vs 130 MB ideal -- the 8 m-blocks sharing one
  // WT n-tile were consecutive bids -> spread over all 8 XCDs, each XCD-L2
  // fetched the tile separately while hidden's 256 MB write stream flushed
  // the LLC. Remap puts all 8 sharers on ONE XCD in 8 consecutive per-XCD
  // slots (co-resident: ~80 blk/XCD in flight; 10 n-tiles x 256 KB = 2.5 MB
  // < 4 MB L2; X = 2 MB fully resident). Bijective: n = xcd*64 + (q>>3).
  int xcd = bid & 7;
  int q = bid >> 3;
  int m0 = (q & 7) * BM;                 // 8 row tiles over B=1024
  int nbase = (xcd * 64 + (q >> 3)) * BN; // 512 col tiles over T*H=65536

  const bf16_t* Aptr = Xb + (size_t)m0 * L_N;
  const bf16_t* Bptr = WT + (size_t)nbase * L_N;

  // staging: lane i copies 16 B; wave covers 16 contiguous 64 B LDS rows
  int srow = lane >> 2;
  int scol = lane & 3;
  size_t soff = (size_t)(wave * 16 + srow) * L_N + scol * 8;

  f32x4_t acc[4][4];
  f32x4_t zero = {0.f, 0.f, 0.f, 0.f};
#pragma unroll
  for (int i = 0; i < 4; i++)
#pragma unroll
    for (int j = 0; j < 4; j++) acc[i][j] = zero;

  int wm = wave >> 1, wn = wave & 1;
  int fr = lane & 15;
  int fq = lane >> 4;

  for (int k0 = 0; k0 < L_N; k0 += BK) {
    const bf16_t* ga = Aptr + soff + k0;
    const bf16_t* gb = Bptr + soff + k0;
    async_load16(ga, &As[wave * 16][0]);
    async_load16(ga + 64 * L_N, &As[64 + wave * 16][0]);
    async_load16(gb, &Bs[wave * 16][0]);
    async_load16(gb + 64 * L_N, &Bs[64 + wave * 16][0]);
    __syncthreads();
    bf16x8_t af[4], bfv[4];
#pragma unroll
    for (int i = 0; i < 4; i++)
      af[i] = *(const bf16x8_t*)&As[wm * 64 + i * 16 + fr][fq * 8];
#pragma unroll
    for (int j = 0; j < 4; j++)
      bfv[j] = *(const bf16x8_t*)&Bs[wn * 64 + j * 16 + fr][fq * 8];
#pragma unroll
    for (int i = 0; i < 4; i++)
#pragma unroll
      for (int j = 0; j < 4; j++)
        acc[i][j] = __builtin_amdgcn_mfma_f32_16x16x32_bf16(af[i], bfv[j], acc[i][j], 0, 0, 0);
    __syncthreads();
  }
  // NOTE on SQ_LDS_BANK_CONFLICT ~1.68e7: this is the b128 structural floor
  // for this fragment pattern (wave's address multiset covers the full
  // 16-row x 64 B region -> 8 rounds/bank no matter the layout; a swizzle
  // only permutes lane->address, not the multiset). Matches m98's value on
  // the same structure. Do not chase it.

  // C/D layout: col = lane&15, row = (lane>>4)*4 + r  [verified m89/m91]
#pragma unroll
  for (int i = 0; i < 4; i++) {
    int gm = m0 + wm * 64 + i * 16 + fq * 4;
#pragma unroll
    for (int j = 0; j < 4; j++) {
      int gn = nbase + wn * 64 + j * 16 + fr;
      HT* outp = hidden + (size_t)gm * NCOL + gn;
#pragma unroll
      for (int r = 0; r < 4; r++) outp[(size_t)r * NCOL] = (HT)acc[i][j][r];
    }
  }
}

// ---------------- helpers shared by the tail kernels ----------------

__device__ __forceinline__ float wave_reduce_sum(float v) {
#pragma unroll
  for (int off = 32; off > 0; off >>= 1) v += __shfl_xor(v, off);
  return v;
}

// order-preserving float->uint key and inverse
__device__ __forceinline__ unsigned f2key(float f) {
  unsigned u = __float_as_uint(f);
  return u ^ ((u >> 31) ? 0xFFFFFFFFu : 0x80000000u);
}
__device__ __forceinline__ float key2f(unsigned k) {
  return __uint_as_float(k ^ ((k >> 31) ? 0x80000000u : 0xFFFFFFFFu));
}

__device__ __forceinline__ int lanes_below(unsigned long long m) {
  return (int)__builtin_amdgcn_mbcnt_hi((unsigned)(m >> 32),
                                        __builtin_amdgcn_mbcnt_lo((unsigned)m, 0u));
}

// f32 path: 2 batches of 4x16B loads — staging peak 16 VGPRs on top of key[32]
__device__ __forceinline__ void load_keys(const float* __restrict__ row, int lane,
                                          unsigned key[32]) {
  const float4* r4 = (const float4*)row;
#pragma unroll
  for (int h = 0; h < 2; h++) {
    float4 v[4];
#pragma unroll
    for (int q = 0; q < 4; q++) v[q] = r4[lane + 64 * (h * 4 + q)];
#pragma unroll
    for (int q = 0; q < 4; q++) {
      int o = (h * 4 + q) * 4;
      key[o + 0] = f2key(v[q].x);
      key[o + 1] = f2key(v[q].y);
      key[o + 2] = f2key(v[q].z);
      key[o + 3] = f2key(v[q].w);
    }
  }
}

__device__ __forceinline__ void load_keys(const bf16_t* __restrict__ row, int lane,
                                          unsigned key[32]) {
  const bf16x8_t* r8 = (const bf16x8_t*)row;
#pragma unroll
  for (int h = 0; h < 2; h++) {
    bf16x8_t v[2];
#pragma unroll
    for (int q = 0; q < 2; q++) v[q] = r8[lane + 64 * (h * 2 + q)];
#pragma unroll
    for (int q = 0; q < 2; q++)
#pragma unroll
      for (int j = 0; j < 8; j++) key[(h * 2 + q) * 8 + j] = f2key((float)v[q][j]);
  }
}

// ---------------- kernel A: top-64 select + sort -> g[B,T,64] f32 ----------------
// (256,3) = 85-VGPR budget; measured need ~60 (key 32 + staging 16 + temps ~12).
template <typename HT>
__global__ __launch_bounds__(256, 3) void topk_select_kernel(
    const HT* __restrict__ hidden, float* __restrict__ g_out) {
  __shared__ unsigned slots[4][K_TOP];
  int t = blockIdx.y;
  int wave = threadIdx.x >> 6;
  int lane = threadIdx.x & 63;
  int b = blockIdx.x * 4 + wave;

  unsigned key[32];
  load_keys(hidden + (size_t)b * NCOL + (size_t)t * H_N, lane, key);

  // exact 64th-largest key: largest thr with count(key >= thr) >= 64
  unsigned thr = 0;
  for (int bit = 31; bit >= 0; --bit) {
    unsigned cand = thr | (1u << bit);
    int c = 0;
#pragma unroll
    for (int i = 0; i < 32; i++) c += (int)__popcll(__ballot(key[i] >= cand));
    if (c >= K_TOP) thr = cand; // wave-uniform
  }

  // compaction via ballot prefix (no atomics, wave-local LDS only)
  int base = 0;
#pragma unroll
  for (int i = 0; i < 32; i++) {
    bool p = key[i] > thr;
    unsigned long long m = __ballot(p);
    if (p) slots[wave][base + lanes_below(m)] = key[i];
    base += (int)__popcll(m);
  }
#pragma unroll
  for (int i = 0; i < 32; i++) {
    bool p = key[i] == thr;
    unsigned long long m = __ballot(p);
    if (p) {
      int pos = base + lanes_below(m);
      if (pos < K_TOP) slots[wave][pos] = key[i];
    }
    base += (int)__popcll(m);
  }

  // 64-lane register bitonic sort, descending (unsigned keys)
  unsigned g = slots[wave][lane];
#pragma unroll
  for (int k = 2; k <= 64; k <<= 1) {
#pragma unroll
    for (int j = k >> 1; j > 0; j >>= 1) {
      unsigned other = (unsigned)__shfl_xor((int)g, j);
      bool keep_max = (((lane & k) == 0) != ((lane & j) != 0));
      unsigned mx = g > other ? g : other;
      unsigned mn = g > other ? other : g;
      g = keep_max ? mx : mn;
    }
  }
  g_out[((size_t)b * T_N + t) * K_TOP + lane] = key2f(g);
}

// ---------------- kernel B: dense + GELU + LN from g ----------------

// Lane owns 4 CONSECUTIVE output cols (4*lane..4*lane+3): W reads are one
// conflict-free ds_read_b128 (16-lane group covers all 32 banks once), and
// bias/gamma/beta/out are float4 accesses.
__device__ __forceinline__ void gelu_ln_store4(f32x4_t y,
                                               const float* __restrict__ gm,
                                               const float* __restrict__ bt,
                                               float* __restrict__ op, int lane) {
  const float is2 = 0.70710678118654752f;
#pragma unroll
  for (int j = 0; j < 4; j++) y[j] = 0.5f * y[j] * (1.f + erff(y[j] * is2));
  float mean = wave_reduce_sum(y[0] + y[1] + y[2] + y[3]) * (1.f / 256.f);
  f32x4_t d;
#pragma unroll
  for (int j = 0; j < 4; j++) d[j] = y[j] - mean;
  float var = wave_reduce_sum(d[0] * d[0] + d[1] * d[1] + d[2] * d[2] + d[3] * d[3]) *
              (1.f / 256.f);
  float rstd = rsqrtf(var + 1e-6f);
  f32x4_t gmv = *(const f32x4_t*)(gm + 4 * lane);
  f32x4_t btv = *(const f32x4_t*)(bt + 4 * lane);
  f32x4_t o;
#pragma unroll
  for (int j = 0; j < 4; j++) o[j] = d[j] * rstd * gmv[j] + btv[j];
  *(f32x4_t*)(op + 4 * lane) = o;
}

// Wd tile (64x256 f32 = 64 KB) in LDS; g broadcast via uniform-address LDS
// reads (replaces the literal-k shfl that forced full unroll). Outer loop is
// #pragma unroll 1: load window is structurally 8 ds_read_b128 + 16 acc
// (~60 regs) -> spill mechanism removed, not tuned around.
__global__ __launch_bounds__(256, 2) void dense_tail_kernel(
    const float* __restrict__ g_in, const float* __restrict__ Wd,
    const float* __restrict__ bd, const float* __restrict__ gamma,
    const float* __restrict__ beta, float* __restrict__ out) {
  __shared__ f32x4_t wlds4[K_TOP * O_N / 4]; // 64 KB, layout [k][64 float4]
  __shared__ f32x4_t glds4[4][4][K_TOP / 4]; // 4 KB: [wave][row][k-chunk]
  int t = blockIdx.y;
  int wave = threadIdx.x >> 6;
  int lane = threadIdx.x & 63;
  int b0 = blockIdx.x * 16 + wave; // rows b0, b0+4, b0+8, b0+12

  // cooperative Wd stage: 4096 float4, 16 per thread (straight copy)
  {
    const f32x4_t* src = (const f32x4_t*)(Wd + (size_t)t * K_TOP * O_N);
#pragma unroll
    for (int i = 0; i < 16; i++)
      wlds4[threadIdx.x + 256 * i] = src[threadIdx.x + 256 * i];
  }

  // stage this wave's 4 g rows into LDS (lane k holds g[k])
  {
    float* g0 = (float*)&glds4[wave][0][0];
    float* g1 = (float*)&glds4[wave][1][0];
    float* g2 = (float*)&glds4[wave][2][0];
    float* g3 = (float*)&glds4[wave][3][0];
    g0[lane] = g_in[((size_t)(b0)*T_N + t) * K_TOP + lane];
    g1[lane] = g_in[((size_t)(b0 + 4) * T_N + t) * K_TOP + lane];
    g2[lane] = g_in[((size_t)(b0 + 8) * T_N + t) * K_TOP + lane];
    g3[lane] = g_in[((size_t)(b0 + 12) * T_N + t) * K_TOP + lane];
  }

  const float* bdt = bd + t * O_N;
  f32x4_t bb = *(const f32x4_t*)(bdt + 4 * lane);
  f32x4_t aA = bb, aB = bb, aC = bb, aD = bb;

  __syncthreads();

#pragma unroll 1
  for (int c = 0; c < K_TOP / 4; c++) {
    f32x4_t gA = glds4[wave][0][c]; // uniform address -> broadcast, no conflict
    f32x4_t gB = glds4[wave][1][c];
    f32x4_t gC = glds4[wave][2][c];
    f32x4_t gD = glds4[wave][3][c];
#pragma unroll
    for (int kk = 0; kk < 4; kk++) {
      f32x4_t w = wlds4[(c * 4 + kk) * 64 + lane];
#pragma unroll
      for (int j = 0; j < 4; j++) {
        aA[j] = fmaf(gA[kk], w[j], aA[j]);
        aB[j] = fmaf(gB[kk], w[j], aB[j]);
        aC[j] = fmaf(gC[kk], w[j], aC[j]);
        aD[j] = fmaf(gD[kk], w[j], aD[j]);
      }
    }
  }

  const float* gm = gamma + t * O_N;
  const float* bt = beta + t * O_N;
  gelu_ln_store4(aA, gm, bt, out + ((size_t)(b0)*T_N + t) * O_N, lane);
  gelu_ln_store4(aB, gm, bt, out + ((size_t)(b0 + 4) * T_N + t) * O_N, lane);
  gelu_ln_store4(aC, gm, bt, out + ((size_t)(b0 + 8) * T_N + t) * O_N, lane);
  gelu_ln_store4(aD, gm, bt, out + ((size_t)(b0 + 12) * T_N + t) * O_N, lane);
}

// ---------------- launch ----------------
extern "C" void kernel_launch(void* const* d_in, const int* in_sizes, int n_in,
                              void* d_out, int out_size, void* d_ws, size_t ws_size,
                              hipStream_t stream) {
  const float* x = (const float*)d_in[0];
  const float* Wt = (const float*)d_in[1];
  const float* Wd = (const float*)d_in[2];
  const float* bd = (const float*)d_in[3];
  const float* gamma = (const float*)d_in[4];
  const float* beta = (const float*)d_in[5];
  float* out = (float*)d_out;

  char* ws = (char*)d_ws;
  size_t sz_wt = (size_t)T_N * H_N * L_N * 2; // 128 MB
  size_t sz_x = (size_t)B_N * L_N * 2;        // 2 MB
  size_t off_h = sz_wt + sz_x;
  size_t sz_h_f32 = (size_t)B_N * NCOL * 4;   // 256 MB
  size_t sz_h_b16 = (size_t)B_N * NCOL * 2;   // 128 MB
  size_t sz_g = (size_t)B_N * T_N * K_TOP * 4; // 8 MB

  bf16_t* WTb = (bf16_t*)ws;
  bf16_t* Xb = (bf16_t*)(ws + sz_wt);

  cvt_x_kernel<<<B_N * L_N / 1024, 256, 0, stream>>>(x, Xb);
  cvt_w_kernel<<<dim3(H_N / 64, L_N / 64, T_N), 256, 0, stream>>>(Wt, WTb);

  if (ws_size >= off_h + sz_h_f32) {
    float* hidden = (float*)(ws + off_h);
    // g buffer: after hidden if it fits, else overlap WT (dead after gemm1)
    float* gbuf = (ws_size >= off_h + sz_h_f32 + sz_g)
                      ? (float*)(ws + off_h + sz_h_f32)
                      : (float*)ws;
    gemm1_kernel<float><<<4096, 256, 0, stream>>>(Xb, WTb, hidden);
    topk_select_kernel<float><<<dim3(B_N / 4, T_N), 256, 0, stream>>>(hidden, gbuf);
    dense_tail_kernel<<<dim3(B_N / 16, T_N), 256, 0, stream>>>(gbuf, Wd, bd, gamma,
                                                               beta, out);
  } else { // fall back to bf16 hidden (270 MB total ws)
    bf16_t* hidden = (bf16_t*)(ws + off_h);
    float* gbuf = (ws_size >= off_h + sz_h_b16 + sz_g)
                      ? (float*)(ws + off_h + sz_h_b16)
                      : (float*)ws;
    gemm1_kernel<bf16_t><<<4096, 256, 0, stream>>>(Xb, WTb, hidden);
    topk_select_kernel<bf16_t><<<dim3(B_N / 4, T_N), 256, 0, stream>>>(hidden, gbuf);
    dense_tail_kernel<<<dim3(B_N / 16, T_N), 256, 0, stream>>>(gbuf, Wd, bd, gamma,
                                                               beta, out);
  }
}

// Round 6
// 779.809 us; speedup vs baseline: 1.0286x; 1.0286x over previous
//
#include <hip/hip_runtime.h>
#include <hip/hip_bf16.h>
#include <math.h>

typedef __bf16 bf16_t;
typedef __bf16 bf16x2_t __attribute__((ext_vector_type(2)));
typedef __bf16 bf16x4_t __attribute__((ext_vector_type(4)));
typedef __bf16 bf16x8_t __attribute__((ext_vector_type(8)));
typedef float f32x4_t __attribute__((ext_vector_type(4)));

#define B_N 1024
#define L_N 1024
#define T_N 32
#define H_N 2048
#define K_TOP 64
#define O_N 256
#define NCOL (T_N * H_N) /* 65536 */

// VGPR-budget rules on gfx950 (R1-R3 post-mortems):
//   __launch_bounds__(256, w) caps VGPRs at 256/w.
//   FULL UNROLL over a deep load loop (VMEM _or_ LDS) lets the compiler
//   batch loads arbitrarily deep -> pressure exceeds any cap -> scratch
//   spill (R1: 5GB, R2: 4.1GB, R3: 2.9GB phantom traffic). Fix is
//   structural: partial unroll + LDS-broadcast instead of literal-k shfl.
// R5: gemm1 XCD remap fixed FETCH (530->115 MB) but NOT duration ->
//   gemm1 is issue-structure-bound (m97 2-barrier loop, ~580 TF). The
//   remaining gemm1 lever is the 8-phase 256^2 schedule. This round:
//   bf16 hidden (halves select fetch, kills its LLC writeback).

// ---------------- conversion: x -> bf16 ----------------
__global__ __launch_bounds__(256) void cvt_x_kernel(const float* __restrict__ x,
                                                    bf16_t* __restrict__ xb) {
  int i = (blockIdx.x * 256 + threadIdx.x) * 4;
  float4 v = *(const float4*)(x + i);
  bf16x4_t o;
  o[0] = (bf16_t)v.x; o[1] = (bf16_t)v.y; o[2] = (bf16_t)v.z; o[3] = (bf16_t)v.w;
  *(bf16x4_t*)(xb + i) = o;
}

// -------- conversion+transpose: Wt [T,L,H] f32 -> WT [T,H,L] bf16 --------
__global__ __launch_bounds__(256) void cvt_w_kernel(const float* __restrict__ W,
                                                    bf16_t* __restrict__ WT) {
  __shared__ float tile[64][65];
  int t = blockIdx.z;
  int h0 = blockIdx.x * 64;
  int l0 = blockIdx.y * 64;
  const float* src = W + (size_t)t * L_N * H_N;
  int hx = threadIdx.x & 63;
  int ly = threadIdx.x >> 6;
#pragma unroll
  for (int r = 0; r < 64; r += 4)
    tile[ly + r][hx] = src[(size_t)(l0 + ly + r) * H_N + h0 + hx];
  __syncthreads();
  bf16_t* dst = WT + (size_t)t * H_N * L_N;
  int lx = (threadIdx.x & 31) * 2;
  int hy = threadIdx.x >> 5;
#pragma unroll
  for (int r = 0; r < 64; r += 8) {
    int h = hy + r;
    bf16x2_t o;
    o[0] = (bf16_t)tile[lx][h];
    o[1] = (bf16_t)tile[lx + 1][h];
    *(bf16x2_t*)(dst + (size_t)(h0 + h) * L_N + l0 + lx) = o;
  }
}

// ---------------- GEMM1: hidden[b, t*2048+h] = sum_l x[b,l]*W[t,l,h] ----------------
#define BM 128
#define BN 128
#define BK 32

__device__ __forceinline__ void async_load16(const void* g, void* l) {
  __builtin_amdgcn_global_load_lds((const __attribute__((address_space(1))) void*)g,
                                   (__attribute__((address_space(3))) void*)l,
                                   16, 0, 0);
}

template <typename HT>
__global__ __launch_bounds__(256) void gemm1_kernel(const bf16_t* __restrict__ Xb,
                                                    const bf16_t* __restrict__ WT,
                                                    HT* __restrict__ hidden) {
  __shared__ bf16_t As[BM][BK]; // [m][k], row = 64 B
  __shared__ bf16_t Bs[BN][BK]; // [n][k], row = 64 B  (WT is already [n][k] in global)
  int tid = threadIdx.x;
  int wave = tid >> 6;
  int lane = tid & 63;
  int bid = blockIdx.x;

  // XCD-aware remap (dispatch model: XCD = bid % 8 round-robin).
  // R5 verified: FETCH 530 -> 115 MB (ideal 130). Keep. Duration was NOT
  // fetch-bound; remaining gemm1 lever is the 8-phase schedule.
  int xcd = bid & 7;
  int q = bid >> 3;
  int m0 = (q & 7) * BM;                 // 8 row tiles over B=1024
  int nbase = (xcd * 64 + (q >> 3)) * BN; // 512 col tiles over T*H=65536

  const bf16_t* Aptr = Xb + (size_t)m0 * L_N;
  const bf16_t* Bptr = WT + (size_t)nbase * L_N;

  // staging: lane i copies 16 B; wave covers 16 contiguous 64 B LDS rows
  int srow = lane >> 2;
  int scol = lane & 3;
  size_t soff = (size_t)(wave * 16 + srow) * L_N + scol * 8;

  f32x4_t acc[4][4];
  f32x4_t zero = {0.f, 0.f, 0.f, 0.f};
#pragma unroll
  for (int i = 0; i < 4; i++)
#pragma unroll
    for (int j = 0; j < 4; j++) acc[i][j] = zero;

  int wm = wave >> 1, wn = wave & 1;
  int fr = lane & 15;
  int fq = lane >> 4;

  for (int k0 = 0; k0 < L_N; k0 += BK) {
    const bf16_t* ga = Aptr + soff + k0;
    const bf16_t* gb = Bptr + soff + k0;
    async_load16(ga, &As[wave * 16][0]);
    async_load16(ga + 64 * L_N, &As[64 + wave * 16][0]);
    async_load16(gb, &Bs[wave * 16][0]);
    async_load16(gb + 64 * L_N, &Bs[64 + wave * 16][0]);
    __syncthreads();
    bf16x8_t af[4], bfv[4];
#pragma unroll
    for (int i = 0; i < 4; i++)
      af[i] = *(const bf16x8_t*)&As[wm * 64 + i * 16 + fr][fq * 8];
#pragma unroll
    for (int j = 0; j < 4; j++)
      bfv[j] = *(const bf16x8_t*)&Bs[wn * 64 + j * 16 + fr][fq * 8];
#pragma unroll
    for (int i = 0; i < 4; i++)
#pragma unroll
      for (int j = 0; j < 4; j++)
        acc[i][j] = __builtin_amdgcn_mfma_f32_16x16x32_bf16(af[i], bfv[j], acc[i][j], 0, 0, 0);
    __syncthreads();
  }
  // NOTE on SQ_LDS_BANK_CONFLICT ~1.68e7: b128 structural floor for this
  // fragment pattern (address multiset covers the full 16-row x 64 B region
  // -> 8 rounds/bank regardless of swizzle). Matches m98. Do not chase.

  // C/D layout: col = lane&15, row = (lane>>4)*4 + r  [verified m89/m91]
#pragma unroll
  for (int i = 0; i < 4; i++) {
    int gm = m0 + wm * 64 + i * 16 + fq * 4;
#pragma unroll
    for (int j = 0; j < 4; j++) {
      int gn = nbase + wn * 64 + j * 16 + fr;
      HT* outp = hidden + (size_t)gm * NCOL + gn;
#pragma unroll
      for (int r = 0; r < 4; r++) outp[(size_t)r * NCOL] = (HT)acc[i][j][r];
    }
  }
}

// ---------------- helpers shared by the tail kernels ----------------

__device__ __forceinline__ float wave_reduce_sum(float v) {
#pragma unroll
  for (int off = 32; off > 0; off >>= 1) v += __shfl_xor(v, off);
  return v;
}

// order-preserving float->uint key and inverse
__device__ __forceinline__ unsigned f2key(float f) {
  unsigned u = __float_as_uint(f);
  return u ^ ((u >> 31) ? 0xFFFFFFFFu : 0x80000000u);
}
__device__ __forceinline__ float key2f(unsigned k) {
  return __uint_as_float(k ^ ((k >> 31) ? 0x80000000u : 0xFFFFFFFFu));
}

__device__ __forceinline__ int lanes_below(unsigned long long m) {
  return (int)__builtin_amdgcn_mbcnt_hi((unsigned)(m >> 32),
                                        __builtin_amdgcn_mbcnt_lo((unsigned)m, 0u));
}

// f32 path: 2 batches of 4x16B loads — staging peak 16 VGPRs on top of key[32]
__device__ __forceinline__ void load_keys(const float* __restrict__ row, int lane,
                                          unsigned key[32]) {
  const float4* r4 = (const float4*)row;
#pragma unroll
  for (int h = 0; h < 2; h++) {
    float4 v[4];
#pragma unroll
    for (int q = 0; q < 4; q++) v[q] = r4[lane + 64 * (h * 4 + q)];
#pragma unroll
    for (int q = 0; q < 4; q++) {
      int o = (h * 4 + q) * 4;
      key[o + 0] = f2key(v[q].x);
      key[o + 1] = f2key(v[q].y);
      key[o + 2] = f2key(v[q].z);
      key[o + 3] = f2key(v[q].w);
    }
  }
}

__device__ __forceinline__ void load_keys(const bf16_t* __restrict__ row, int lane,
                                          unsigned key[32]) {
  const bf16x8_t* r8 = (const bf16x8_t*)row;
#pragma unroll
  for (int h = 0; h < 2; h++) {
    bf16x8_t v[2];
#pragma unroll
    for (int q = 0; q < 2; q++) v[q] = r8[lane + 64 * (h * 2 + q)];
#pragma unroll
    for (int q = 0; q < 2; q++)
#pragma unroll
      for (int j = 0; j < 8; j++) key[(h * 2 + q) * 8 + j] = f2key((float)v[q][j]);
  }
}

// ---------------- kernel A: top-64 select + sort -> g[B,T,64] f32 ----------------
// (256,3) = 85-VGPR budget; measured need ~60 (key 32 + staging 16 + temps ~12).
template <typename HT>
__global__ __launch_bounds__(256, 3) void topk_select_kernel(
    const HT* __restrict__ hidden, float* __restrict__ g_out) {
  __shared__ unsigned slots[4][K_TOP];
  int t = blockIdx.y;
  int wave = threadIdx.x >> 6;
  int lane = threadIdx.x & 63;
  int b = blockIdx.x * 4 + wave;

  unsigned key[32];
  load_keys(hidden + (size_t)b * NCOL + (size_t)t * H_N, lane, key);

  // exact 64th-largest key: largest thr with count(key >= thr) >= 64
  unsigned thr = 0;
  for (int bit = 31; bit >= 0; --bit) {
    unsigned cand = thr | (1u << bit);
    int c = 0;
#pragma unroll
    for (int i = 0; i < 32; i++) c += (int)__popcll(__ballot(key[i] >= cand));
    if (c >= K_TOP) thr = cand; // wave-uniform
  }

  // compaction via ballot prefix (no atomics, wave-local LDS only)
  int base = 0;
#pragma unroll
  for (int i = 0; i < 32; i++) {
    bool p = key[i] > thr;
    unsigned long long m = __ballot(p);
    if (p) slots[wave][base + lanes_below(m)] = key[i];
    base += (int)__popcll(m);
  }
#pragma unroll
  for (int i = 0; i < 32; i++) {
    bool p = key[i] == thr;
    unsigned long long m = __ballot(p);
    if (p) {
      int pos = base + lanes_below(m);
      if (pos < K_TOP) slots[wave][pos] = key[i];
    }
    base += (int)__popcll(m);
  }

  // 64-lane register bitonic sort, descending (unsigned keys)
  unsigned g = slots[wave][lane];
#pragma unroll
  for (int k = 2; k <= 64; k <<= 1) {
#pragma unroll
    for (int j = k >> 1; j > 0; j >>= 1) {
      unsigned other = (unsigned)__shfl_xor((int)g, j);
      bool keep_max = (((lane & k) == 0) != ((lane & j) != 0));
      unsigned mx = g > other ? g : other;
      unsigned mn = g > other ? other : g;
      g = keep_max ? mx : mn;
    }
  }
  g_out[((size_t)b * T_N + t) * K_TOP + lane] = key2f(g);
}

// ---------------- kernel B: dense + GELU + LN from g ----------------

// Lane owns 4 CONSECUTIVE output cols (4*lane..4*lane+3): W reads are one
// conflict-free ds_read_b128 (16-lane group covers all 32 banks once), and
// bias/gamma/beta/out are float4 accesses.
__device__ __forceinline__ void gelu_ln_store4(f32x4_t y,
                                               const float* __restrict__ gm,
                                               const float* __restrict__ bt,
                                               float* __restrict__ op, int lane) {
  const float is2 = 0.70710678118654752f;
#pragma unroll
  for (int j = 0; j < 4; j++) y[j] = 0.5f * y[j] * (1.f + erff(y[j] * is2));
  float mean = wave_reduce_sum(y[0] + y[1] + y[2] + y[3]) * (1.f / 256.f);
  f32x4_t d;
#pragma unroll
  for (int j = 0; j < 4; j++) d[j] = y[j] - mean;
  float var = wave_reduce_sum(d[0] * d[0] + d[1] * d[1] + d[2] * d[2] + d[3] * d[3]) *
              (1.f / 256.f);
  float rstd = rsqrtf(var + 1e-6f);
  f32x4_t gmv = *(const f32x4_t*)(gm + 4 * lane);
  f32x4_t btv = *(const f32x4_t*)(bt + 4 * lane);
  f32x4_t o;
#pragma unroll
  for (int j = 0; j < 4; j++) o[j] = d[j] * rstd * gmv[j] + btv[j];
  *(f32x4_t*)(op + 4 * lane) = o;
}

// Wd tile (64x256 f32 = 64 KB) in LDS; g broadcast via uniform-address LDS
// reads (replaces the literal-k shfl that forced full unroll). Outer loop is
// #pragma unroll 1: load window is structurally 8 ds_read_b128 + 16 acc
// (~60 regs) -> spill mechanism removed, not tuned around.
__global__ __launch_bounds__(256, 2) void dense_tail_kernel(
    const float* __restrict__ g_in, const float* __restrict__ Wd,
    const float* __restrict__ bd, const float* __restrict__ gamma,
    const float* __restrict__ beta, float* __restrict__ out) {
  __shared__ f32x4_t wlds4[K_TOP * O_N / 4]; // 64 KB, layout [k][64 float4]
  __shared__ f32x4_t glds4[4][4][K_TOP / 4]; // 4 KB: [wave][row][k-chunk]
  int t = blockIdx.y;
  int wave = threadIdx.x >> 6;
  int lane = threadIdx.x & 63;
  int b0 = blockIdx.x * 16 + wave; // rows b0, b0+4, b0+8, b0+12

  // cooperative Wd stage: 4096 float4, 16 per thread (straight copy)
  {
    const f32x4_t* src = (const f32x4_t*)(Wd + (size_t)t * K_TOP * O_N);
#pragma unroll
    for (int i = 0; i < 16; i++)
      wlds4[threadIdx.x + 256 * i] = src[threadIdx.x + 256 * i];
  }

  // stage this wave's 4 g rows into LDS (lane k holds g[k])
  {
    float* g0 = (float*)&glds4[wave][0][0];
    float* g1 = (float*)&glds4[wave][1][0];
    float* g2 = (float*)&glds4[wave][2][0];
    float* g3 = (float*)&glds4[wave][3][0];
    g0[lane] = g_in[((size_t)(b0)*T_N + t) * K_TOP + lane];
    g1[lane] = g_in[((size_t)(b0 + 4) * T_N + t) * K_TOP + lane];
    g2[lane] = g_in[((size_t)(b0 + 8) * T_N + t) * K_TOP + lane];
    g3[lane] = g_in[((size_t)(b0 + 12) * T_N + t) * K_TOP + lane];
  }

  const float* bdt = bd + t * O_N;
  f32x4_t bb = *(const f32x4_t*)(bdt + 4 * lane);
  f32x4_t aA = bb, aB = bb, aC = bb, aD = bb;

  __syncthreads();

#pragma unroll 1
  for (int c = 0; c < K_TOP / 4; c++) {
    f32x4_t gA = glds4[wave][0][c]; // uniform address -> broadcast, no conflict
    f32x4_t gB = glds4[wave][1][c];
    f32x4_t gC = glds4[wave][2][c];
    f32x4_t gD = glds4[wave][3][c];
#pragma unroll
    for (int kk = 0; kk < 4; kk++) {
      f32x4_t w = wlds4[(c * 4 + kk) * 64 + lane];
#pragma unroll
      for (int j = 0; j < 4; j++) {
        aA[j] = fmaf(gA[kk], w[j], aA[j]);
        aB[j] = fmaf(gB[kk], w[j], aB[j]);
        aC[j] = fmaf(gC[kk], w[j], aC[j]);
        aD[j] = fmaf(gD[kk], w[j], aD[j]);
      }
    }
  }

  const float* gm = gamma + t * O_N;
  const float* bt = beta + t * O_N;
  gelu_ln_store4(aA, gm, bt, out + ((size_t)(b0)*T_N + t) * O_N, lane);
  gelu_ln_store4(aB, gm, bt, out + ((size_t)(b0 + 4) * T_N + t) * O_N, lane);
  gelu_ln_store4(aC, gm, bt, out + ((size_t)(b0 + 8) * T_N + t) * O_N, lane);
  gelu_ln_store4(aD, gm, bt, out + ((size_t)(b0 + 12) * T_N + t) * O_N, lane);
}

// ---------------- launch ----------------
extern "C" void kernel_launch(void* const* d_in, const int* in_sizes, int n_in,
                              void* d_out, int out_size, void* d_ws, size_t ws_size,
                              hipStream_t stream) {
  const float* x = (const float*)d_in[0];
  const float* Wt = (const float*)d_in[1];
  const float* Wd = (const float*)d_in[2];
  const float* bd = (const float*)d_in[3];
  const float* gamma = (const float*)d_in[4];
  const float* beta = (const float*)d_in[5];
  float* out = (float*)d_out;

  char* ws = (char*)d_ws;
  size_t sz_wt = (size_t)T_N * H_N * L_N * 2; // 128 MB
  size_t sz_x = (size_t)B_N * L_N * 2;        // 2 MB
  size_t off_h = sz_wt + sz_x;
  size_t sz_h_b16 = (size_t)B_N * NCOL * 2;   // 128 MB
  size_t sz_g = (size_t)B_N * T_N * K_TOP * 4; // 8 MB

  bf16_t* WTb = (bf16_t*)ws;
  bf16_t* Xb = (bf16_t*)(ws + sz_wt);

  cvt_x_kernel<<<B_N * L_N / 1024, 256, 0, stream>>>(x, Xb);
  cvt_w_kernel<<<dim3(H_N / 64, L_N / 64, T_N), 256, 0, stream>>>(Wt, WTb);

  // bf16 hidden (R6 change): 128 MB fits the 256 MiB LLC with headroom ->
  // select's fetch halves AND its dirty write-back disappears; gemm1's
  // WRITE halves. Accuracy arithmetic: adds ~0.01 to absmax (bf16 rounding
  // of top-64 values, sqrt(64)*0.01*0.079 ~ 0.006 pre-LN). If absmax
  // fails, revert to f32 hidden and take the 8-phase gemm1 rewrite instead.
  bf16_t* hidden = (bf16_t*)(ws + off_h);
  float* gbuf = (ws_size >= off_h + sz_h_b16 + sz_g)
                    ? (float*)(ws + off_h + sz_h_b16)
                    : (float*)ws; // overlap WT (dead after gemm1)
  gemm1_kernel<bf16_t><<<4096, 256, 0, stream>>>(Xb, WTb, hidden);
  topk_select_kernel<bf16_t><<<dim3(B_N / 4, T_N), 256, 0, stream>>>(hidden, gbuf);
  dense_tail_kernel<<<dim3(B_N / 16, T_N), 256, 0, stream>>>(gbuf, Wd, bd, gamma,
                                                             beta, out);
}

// Round 7
// 719.044 us; speedup vs baseline: 1.1156x; 1.0845x over previous
//
#include <hip/hip_runtime.h>
#include <hip/hip_bf16.h>
#include <math.h>

typedef __bf16 bf16_t;
typedef __bf16 bf16x2_t __attribute__((ext_vector_type(2)));
typedef __bf16 bf16x4_t __attribute__((ext_vector_type(4)));
typedef __bf16 bf16x8_t __attribute__((ext_vector_type(8)));
typedef float f32x4_t __attribute__((ext_vector_type(4)));
typedef unsigned short u16;
typedef u16 u16x8 __attribute__((ext_vector_type(8)));

#define B_N 1024
#define L_N 1024
#define T_N 32
#define H_N 2048
#define K_TOP 64
#define O_N 256
#define NCOL (T_N * H_N) /* 65536 */

// Session journal (gfx950):
// R1-R3: __launch_bounds__(256,w) caps VGPR at 256/w. FULL UNROLL over a
//   deep load loop lets the compiler batch loads past any cap -> scratch
//   spill. Structural fix: partial unroll + LDS broadcast.
// R5: gemm1 XCD remap fixed FETCH (530->115 MB) but not duration ->
//   gemm1 is issue-structure-bound (m97 2-barrier loop, ~580 TF eff).
//   Next gemm1 lever: 8-phase 256^2 schedule (guide 5: 1.7x).
// R6: bf16 hidden: absmax unchanged, gemm1 WRITE halved. Select proved
//   NOT fetch-bound -> its cost is the serial ballot threshold search.
//   Accounting: cvt_w and select each ~200-250 us hiding under gemm1's
//   top-5. R7: vectorize cvt_w (was scalar 4B = ~1.8 TB/s) + 16-bit
//   key select (bf16 keys have 16 significant bits -> halve search).

// ---------------- conversion: x -> bf16 ----------------
__global__ __launch_bounds__(256) void cvt_x_kernel(const float* __restrict__ x,
                                                    bf16_t* __restrict__ xb) {
  int i = (blockIdx.x * 256 + threadIdx.x) * 4;
  float4 v = *(const float4*)(x + i);
  bf16x4_t o;
  o[0] = (bf16_t)v.x; o[1] = (bf16_t)v.y; o[2] = (bf16_t)v.z; o[3] = (bf16_t)v.w;
  *(bf16x4_t*)(xb + i) = o;
}

// -------- conversion+transpose: Wt [T,L,H] f32 -> WT [T,H,L] bf16 --------
// R7: vectorized. Reads float4 (16 B/lane), writes bf16x8 (16 B/lane).
// LDS tile [64][65]: write-phase column reads have bank stride 65 % 32 = 1
// -> <=2-way aliasing (free, m136). Global write: 8 lanes x 16 B = 128 B
// contiguous per h-row.
__global__ __launch_bounds__(256) void cvt_w_kernel(const float* __restrict__ W,
                                                    bf16_t* __restrict__ WT) {
  __shared__ float tile[64][65];
  int t = blockIdx.z;
  int h0 = blockIdx.x * 64;
  int l0 = blockIdx.y * 64;
  const float* src = W + (size_t)t * L_N * H_N;
  int hx4 = (threadIdx.x & 15) * 4;
  int ly = threadIdx.x >> 4; // 0..15
#pragma unroll
  for (int r = 0; r < 64; r += 16) {
    float4 v = *(const float4*)(src + (size_t)(l0 + ly + r) * H_N + h0 + hx4);
    tile[ly + r][hx4 + 0] = v.x;
    tile[ly + r][hx4 + 1] = v.y;
    tile[ly + r][hx4 + 2] = v.z;
    tile[ly + r][hx4 + 3] = v.w;
  }
  __syncthreads();
  bf16_t* dst = WT + (size_t)t * H_N * L_N;
  int lx = (threadIdx.x & 7) * 8;
  int hy = threadIdx.x >> 3; // 0..31
#pragma unroll
  for (int r = 0; r < 64; r += 32) {
    int h = hy + r;
    bf16x8_t o;
#pragma unroll
    for (int j = 0; j < 8; j++) o[j] = (bf16_t)tile[lx + j][h];
    *(bf16x8_t*)(dst + (size_t)(h0 + h) * L_N + l0 + lx) = o;
  }
}

// ---------------- GEMM1: hidden[b, t*2048+h] = sum_l x[b,l]*W[t,l,h] ----------------
#define BM 128
#define BN 128
#define BK 32

__device__ __forceinline__ void async_load16(const void* g, void* l) {
  __builtin_amdgcn_global_load_lds((const __attribute__((address_space(1))) void*)g,
                                   (__attribute__((address_space(3))) void*)l,
                                   16, 0, 0);
}

template <typename HT>
__global__ __launch_bounds__(256) void gemm1_kernel(const bf16_t* __restrict__ Xb,
                                                    const bf16_t* __restrict__ WT,
                                                    HT* __restrict__ hidden) {
  __shared__ bf16_t As[BM][BK]; // [m][k], row = 64 B
  __shared__ bf16_t Bs[BN][BK]; // [n][k], row = 64 B  (WT is already [n][k] in global)
  int tid = threadIdx.x;
  int wave = tid >> 6;
  int lane = tid & 63;
  int bid = blockIdx.x;

  // XCD-aware remap (XCD = bid % 8 round-robin). R5 verified: FETCH
  // 530 -> 115 MB (ideal 130). Keep.
  int xcd = bid & 7;
  int q = bid >> 3;
  int m0 = (q & 7) * BM;                 // 8 row tiles over B=1024
  int nbase = (xcd * 64 + (q >> 3)) * BN; // 512 col tiles over T*H=65536

  const bf16_t* Aptr = Xb + (size_t)m0 * L_N;
  const bf16_t* Bptr = WT + (size_t)nbase * L_N;

  // staging: lane i copies 16 B; wave covers 16 contiguous 64 B LDS rows
  int srow = lane >> 2;
  int scol = lane & 3;
  size_t soff = (size_t)(wave * 16 + srow) * L_N + scol * 8;

  f32x4_t acc[4][4];
  f32x4_t zero = {0.f, 0.f, 0.f, 0.f};
#pragma unroll
  for (int i = 0; i < 4; i++)
#pragma unroll
    for (int j = 0; j < 4; j++) acc[i][j] = zero;

  int wm = wave >> 1, wn = wave & 1;
  int fr = lane & 15;
  int fq = lane >> 4;

  for (int k0 = 0; k0 < L_N; k0 += BK) {
    const bf16_t* ga = Aptr + soff + k0;
    const bf16_t* gb = Bptr + soff + k0;
    async_load16(ga, &As[wave * 16][0]);
    async_load16(ga + 64 * L_N, &As[64 + wave * 16][0]);
    async_load16(gb, &Bs[wave * 16][0]);
    async_load16(gb + 64 * L_N, &Bs[64 + wave * 16][0]);
    __syncthreads();
    bf16x8_t af[4], bfv[4];
#pragma unroll
    for (int i = 0; i < 4; i++)
      af[i] = *(const bf16x8_t*)&As[wm * 64 + i * 16 + fr][fq * 8];
#pragma unroll
    for (int j = 0; j < 4; j++)
      bfv[j] = *(const bf16x8_t*)&Bs[wn * 64 + j * 16 + fr][fq * 8];
#pragma unroll
    for (int i = 0; i < 4; i++)
#pragma unroll
      for (int j = 0; j < 4; j++)
        acc[i][j] = __builtin_amdgcn_mfma_f32_16x16x32_bf16(af[i], bfv[j], acc[i][j], 0, 0, 0);
    __syncthreads();
  }
  // SQ_LDS_BANK_CONFLICT ~1.68e7 is the b128 structural floor for this
  // fragment pattern (matches m98). Do not chase.

  // C/D layout: col = lane&15, row = (lane>>4)*4 + r  [verified m89/m91]
#pragma unroll
  for (int i = 0; i < 4; i++) {
    int gm = m0 + wm * 64 + i * 16 + fq * 4;
#pragma unroll
    for (int j = 0; j < 4; j++) {
      int gn = nbase + wn * 64 + j * 16 + fr;
      HT* outp = hidden + (size_t)gm * NCOL + gn;
#pragma unroll
      for (int r = 0; r < 4; r++) outp[(size_t)r * NCOL] = (HT)acc[i][j][r];
    }
  }
}

// ---------------- helpers shared by the tail kernels ----------------

__device__ __forceinline__ float wave_reduce_sum(float v) {
#pragma unroll
  for (int off = 32; off > 0; off >>= 1) v += __shfl_xor(v, off);
  return v;
}

__device__ __forceinline__ int lanes_below(unsigned long long m) {
  return (int)__builtin_amdgcn_mbcnt_hi((unsigned)(m >> 32),
                                        __builtin_amdgcn_mbcnt_lo((unsigned)m, 0u));
}

// ---------------- kernel A: top-64 select + sort -> g[B,T,64] f32 ----------------
// R7: 16-bit keys. hidden is bf16, so the order-preserving key has only 16
// significant bits: k16 = bits ^ (sign ? 0xFFFF : 0x8000). Threshold search
// runs over 16 bits (was 32) -> 512 ballots instead of 1024. Selection is
// exact-arithmetic-identical to the f32-key version.
// (256,3) = 85-VGPR budget; need ~60 (key 32 + staging + temps).
__global__ __launch_bounds__(256, 3) void topk_select_kernel(
    const bf16_t* __restrict__ hidden, float* __restrict__ g_out) {
  __shared__ unsigned slots[4][K_TOP];
  int t = blockIdx.y;
  int wave = threadIdx.x >> 6;
  int lane = threadIdx.x & 63;
  int b = blockIdx.x * 4 + wave;

  unsigned key[32];
  {
    const u16x8* r8 = (const u16x8*)(hidden + (size_t)b * NCOL + (size_t)t * H_N);
#pragma unroll
    for (int h = 0; h < 2; h++) {
      u16x8 v[2];
#pragma unroll
      for (int qq = 0; qq < 2; qq++) v[qq] = r8[lane + 64 * (h * 2 + qq)];
#pragma unroll
      for (int qq = 0; qq < 2; qq++)
#pragma unroll
        for (int j = 0; j < 8; j++) {
          unsigned u = v[qq][j];
          key[(h * 2 + qq) * 8 + j] = u ^ ((u >> 15) ? 0xFFFFu : 0x8000u);
        }
    }
  }

  // exact 64th-largest key: largest thr with count(key >= thr) >= 64
  unsigned thr = 0;
  for (int bit = 15; bit >= 0; --bit) {
    unsigned cand = thr | (1u << bit);
    int c = 0;
#pragma unroll
    for (int i = 0; i < 32; i++) c += (int)__popcll(__ballot(key[i] >= cand));
    if (c >= K_TOP) thr = cand; // wave-uniform
  }

  // compaction via ballot prefix (no atomics, wave-local LDS only)
  int base = 0;
#pragma unroll
  for (int i = 0; i < 32; i++) {
    bool p = key[i] > thr;
    unsigned long long m = __ballot(p);
    if (p) slots[wave][base + lanes_below(m)] = key[i];
    base += (int)__popcll(m);
  }
#pragma unroll
  for (int i = 0; i < 32; i++) {
    bool p = key[i] == thr;
    unsigned long long m = __ballot(p);
    if (p) {
      int pos = base + lanes_below(m);
      if (pos < K_TOP) slots[wave][pos] = key[i];
    }
    base += (int)__popcll(m);
  }

  // 64-lane register bitonic sort, descending (16-bit keys in u32)
  unsigned g = slots[wave][lane];
#pragma unroll
  for (int k = 2; k <= 64; k <<= 1) {
#pragma unroll
    for (int j = k >> 1; j > 0; j >>= 1) {
      unsigned other = (unsigned)__shfl_xor((int)g, j);
      bool keep_max = (((lane & k) == 0) != ((lane & j) != 0));
      unsigned mx = g > other ? g : other;
      unsigned mn = g > other ? other : g;
      g = keep_max ? mx : mn;
    }
  }
  // key16 -> bf16 bits -> f32
  unsigned u = g ^ ((g >> 15) ? 0x8000u : 0xFFFFu);
  g_out[((size_t)b * T_N + t) * K_TOP + lane] = __uint_as_float(u << 16);
}

// ---------------- kernel B: dense + GELU + LN from g ----------------

// Lane owns 4 CONSECUTIVE output cols (4*lane..4*lane+3): W reads are one
// conflict-free ds_read_b128, bias/gamma/beta/out are float4 accesses.
__device__ __forceinline__ void gelu_ln_store4(f32x4_t y,
                                               const float* __restrict__ gm,
                                               const float* __restrict__ bt,
                                               float* __restrict__ op, int lane) {
  const float is2 = 0.70710678118654752f;
#pragma unroll
  for (int j = 0; j < 4; j++) y[j] = 0.5f * y[j] * (1.f + erff(y[j] * is2));
  float mean = wave_reduce_sum(y[0] + y[1] + y[2] + y[3]) * (1.f / 256.f);
  f32x4_t d;
#pragma unroll
  for (int j = 0; j < 4; j++) d[j] = y[j] - mean;
  float var = wave_reduce_sum(d[0] * d[0] + d[1] * d[1] + d[2] * d[2] + d[3] * d[3]) *
              (1.f / 256.f);
  float rstd = rsqrtf(var + 1e-6f);
  f32x4_t gmv = *(const f32x4_t*)(gm + 4 * lane);
  f32x4_t btv = *(const f32x4_t*)(bt + 4 * lane);
  f32x4_t o;
#pragma unroll
  for (int j = 0; j < 4; j++) o[j] = d[j] * rstd * gmv[j] + btv[j];
  *(f32x4_t*)(op + 4 * lane) = o;
}

// Wd tile (64x256 f32 = 64 KB) in LDS; g broadcast via uniform-address LDS
// reads. Outer loop #pragma unroll 1: load window structurally bounded
// (8 ds_read_b128 + 16 acc ~ 60 regs) -> no spill (R4 verified).
__global__ __launch_bounds__(256, 2) void dense_tail_kernel(
    const float* __restrict__ g_in, const float* __restrict__ Wd,
    const float* __restrict__ bd, const float* __restrict__ gamma,
    const float* __restrict__ beta, float* __restrict__ out) {
  __shared__ f32x4_t wlds4[K_TOP * O_N / 4]; // 64 KB, layout [k][64 float4]
  __shared__ f32x4_t glds4[4][4][K_TOP / 4]; // 4 KB: [wave][row][k-chunk]
  int t = blockIdx.y;
  int wave = threadIdx.x >> 6;
  int lane = threadIdx.x & 63;
  int b0 = blockIdx.x * 16 + wave; // rows b0, b0+4, b0+8, b0+12

  // cooperative Wd stage: 4096 float4, 16 per thread (straight copy)
  {
    const f32x4_t* src = (const f32x4_t*)(Wd + (size_t)t * K_TOP * O_N);
#pragma unroll
    for (int i = 0; i < 16; i++)
      wlds4[threadIdx.x + 256 * i] = src[threadIdx.x + 256 * i];
  }

  // stage this wave's 4 g rows into LDS (lane k holds g[k])
  {
    float* g0 = (float*)&glds4[wave][0][0];
    float* g1 = (float*)&glds4[wave][1][0];
    float* g2 = (float*)&glds4[wave][2][0];
    float* g3 = (float*)&glds4[wave][3][0];
    g0[lane] = g_in[((size_t)(b0)*T_N + t) * K_TOP + lane];
    g1[lane] = g_in[((size_t)(b0 + 4) * T_N + t) * K_TOP + lane];
    g2[lane] = g_in[((size_t)(b0 + 8) * T_N + t) * K_TOP + lane];
    g3[lane] = g_in[((size_t)(b0 + 12) * T_N + t) * K_TOP + lane];
  }

  const float* bdt = bd + t * O_N;
  f32x4_t bb = *(const f32x4_t*)(bdt + 4 * lane);
  f32x4_t aA = bb, aB = bb, aC = bb, aD = bb;

  __syncthreads();

#pragma unroll 1
  for (int c = 0; c < K_TOP / 4; c++) {
    f32x4_t gA = glds4[wave][0][c]; // uniform address -> broadcast, no conflict
    f32x4_t gB = glds4[wave][1][c];
    f32x4_t gC = glds4[wave][2][c];
    f32x4_t gD = glds4[wave][3][c];
#pragma unroll
    for (int kk = 0; kk < 4; kk++) {
      f32x4_t w = wlds4[(c * 4 + kk) * 64 + lane];
#pragma unroll
      for (int j = 0; j < 4; j++) {
        aA[j] = fmaf(gA[kk], w[j], aA[j]);
        aB[j] = fmaf(gB[kk], w[j], aB[j]);
        aC[j] = fmaf(gC[kk], w[j], aC[j]);
        aD[j] = fmaf(gD[kk], w[j], aD[j]);
      }
    }
  }

  const float* gm = gamma + t * O_N;
  const float* bt = beta + t * O_N;
  gelu_ln_store4(aA, gm, bt, out + ((size_t)(b0)*T_N + t) * O_N, lane);
  gelu_ln_store4(aB, gm, bt, out + ((size_t)(b0 + 4) * T_N + t) * O_N, lane);
  gelu_ln_store4(aC, gm, bt, out + ((size_t)(b0 + 8) * T_N + t) * O_N, lane);
  gelu_ln_store4(aD, gm, bt, out + ((size_t)(b0 + 12) * T_N + t) * O_N, lane);
}

// ---------------- launch ----------------
extern "C" void kernel_launch(void* const* d_in, const int* in_sizes, int n_in,
                              void* d_out, int out_size, void* d_ws, size_t ws_size,
                              hipStream_t stream) {
  const float* x = (const float*)d_in[0];
  const float* Wt = (const float*)d_in[1];
  const float* Wd = (const float*)d_in[2];
  const float* bd = (const float*)d_in[3];
  const float* gamma = (const float*)d_in[4];
  const float* beta = (const float*)d_in[5];
  float* out = (float*)d_out;

  char* ws = (char*)d_ws;
  size_t sz_wt = (size_t)T_N * H_N * L_N * 2; // 128 MB
  size_t sz_x = (size_t)B_N * L_N * 2;        // 2 MB
  size_t off_h = sz_wt + sz_x;
  size_t sz_h_b16 = (size_t)B_N * NCOL * 2;   // 128 MB
  size_t sz_g = (size_t)B_N * T_N * K_TOP * 4; // 8 MB

  bf16_t* WTb = (bf16_t*)ws;
  bf16_t* Xb = (bf16_t*)(ws + sz_wt);

  cvt_x_kernel<<<B_N * L_N / 1024, 256, 0, stream>>>(x, Xb);
  cvt_w_kernel<<<dim3(H_N / 64, L_N / 64, T_N), 256, 0, stream>>>(Wt, WTb);

  bf16_t* hidden = (bf16_t*)(ws + off_h);
  float* gbuf = (ws_size >= off_h + sz_h_b16 + sz_g)
                    ? (float*)(ws + off_h + sz_h_b16)
                    : (float*)ws; // overlap WT (dead after gemm1)
  gemm1_kernel<bf16_t><<<4096, 256, 0, stream>>>(Xb, WTb, hidden);
  topk_select_kernel<<<dim3(B_N / 4, T_N), 256, 0, stream>>>(hidden, gbuf);
  dense_tail_kernel<<<dim3(B_N / 16, T_N), 256, 0, stream>>>(gbuf, Wd, bd, gamma,
                                                             beta, out);
}

// Round 8
// 706.209 us; speedup vs baseline: 1.1358x; 1.0182x over previous
//
#include <hip/hip_runtime.h>
#include <hip/hip_bf16.h>
#include <math.h>

typedef __bf16 bf16_t;
typedef __bf16 bf16x2_t __attribute__((ext_vector_type(2)));
typedef __bf16 bf16x4_t __attribute__((ext_vector_type(4)));
typedef __bf16 bf16x8_t __attribute__((ext_vector_type(8)));
typedef float f32x4_t __attribute__((ext_vector_type(4)));
typedef unsigned short u16;
typedef u16 u16x8 __attribute__((ext_vector_type(8)));

#define B_N 1024
#define L_N 1024
#define T_N 32
#define H_N 2048
#define K_TOP 64
#define O_N 256
#define NCOL (T_N * H_N) /* 65536 */

// Session journal (gfx950):
// R1-R3: __launch_bounds__(256,w) caps VGPR at 256/w. FULL UNROLL over a
//   deep load loop batches loads past any cap -> scratch spill. Fix is
//   structural (partial unroll + LDS broadcast), not cap tuning.
// R5: gemm1 XCD remap: FETCH 530->115 MB (ideal 130) but duration flat ->
//   gemm1 is issue/structure-bound (2-barrier loop, ~613 TF eff).
// R6: bf16 hidden: absmax unchanged; select proved not fetch-bound.
// R7: budget reconciliation: controllable kernels ~460 us of 719; ~200 us
//   is harness tax (memsets/launch overhead, not visible in top-5).
//   T2 LDS swizzle on 2-phase: measured NULL per guide (m230/m252) - the
//   8-way fragment-read conflict hides under stage+barrier critical path.
// R8 plan notes - derived 8-phase schedule (for a future round if BK=64
//   underdelivers): half-tile lead S=7, 8 LDS slots (slot = h mod 8); per
//   phase: {ds_read ONE half-tile -> regs; 16 MFMA consuming regs read 1-2
//   phases earlier; stage 1 half-tile (2 gload_lds/thread); barrier};
//   vmcnt(6) at K-tile boundaries only; prologue stages 7 half-tiles with
//   vmcnt(4) after 4, vmcnt(6) after +3; epilogue drains 4->2->0.
//   Expected gain at K=1024 is only 1.10-1.29x (m248) - modest.

// ---------------- conversion: x -> bf16 ----------------
__global__ __launch_bounds__(256) void cvt_x_kernel(const float* __restrict__ x,
                                                    bf16_t* __restrict__ xb) {
  int i = (blockIdx.x * 256 + threadIdx.x) * 4;
  float4 v = *(const float4*)(x + i);
  bf16x4_t o;
  o[0] = (bf16_t)v.x; o[1] = (bf16_t)v.y; o[2] = (bf16_t)v.z; o[3] = (bf16_t)v.w;
  *(bf16x4_t*)(xb + i) = o;
}

// -------- conversion+transpose: Wt [T,L,H] f32 -> WT [T,H,L] bf16 --------
// Vectorized (R7): float4 reads, bf16x8 writes. ~80 us vs 61 ideal; leave.
__global__ __launch_bounds__(256) void cvt_w_kernel(const float* __restrict__ W,
                                                    bf16_t* __restrict__ WT) {
  __shared__ float tile[64][65];
  int t = blockIdx.z;
  int h0 = blockIdx.x * 64;
  int l0 = blockIdx.y * 64;
  const float* src = W + (size_t)t * L_N * H_N;
  int hx4 = (threadIdx.x & 15) * 4;
  int ly = threadIdx.x >> 4; // 0..15
#pragma unroll
  for (int r = 0; r < 64; r += 16) {
    float4 v = *(const float4*)(src + (size_t)(l0 + ly + r) * H_N + h0 + hx4);
    tile[ly + r][hx4 + 0] = v.x;
    tile[ly + r][hx4 + 1] = v.y;
    tile[ly + r][hx4 + 2] = v.z;
    tile[ly + r][hx4 + 3] = v.w;
  }
  __syncthreads();
  bf16_t* dst = WT + (size_t)t * H_N * L_N;
  int lx = (threadIdx.x & 7) * 8;
  int hy = threadIdx.x >> 3; // 0..31
#pragma unroll
  for (int r = 0; r < 64; r += 32) {
    int h = hy + r;
    bf16x8_t o;
#pragma unroll
    for (int j = 0; j < 8; j++) o[j] = (bf16_t)tile[lx + j][h];
    *(bf16x8_t*)(dst + (size_t)(h0 + h) * L_N + l0 + lx) = o;
  }
}

// ---------------- GEMM1: hidden[b, t*2048+h] = sum_l x[b,l]*W[t,l,h] ----------------
// R8: BK 32 -> 64. Halves the barrier-drain count (32 -> 16 K-steps), the
// dominant overhead of the 2-phase loop (m233: stage+vmcnt+barrier ~72% of
// critical path; per-drain cost is latency-dominated ~= constant).
#define BM 128
#define BN 128
#define BK 64

__device__ __forceinline__ void async_load16(const void* g, void* l) {
  __builtin_amdgcn_global_load_lds((const __attribute__((address_space(1))) void*)g,
                                   (__attribute__((address_space(3))) void*)l,
                                   16, 0, 0);
}

template <typename HT>
__global__ __launch_bounds__(256) void gemm1_kernel(const bf16_t* __restrict__ Xb,
                                                    const bf16_t* __restrict__ WT,
                                                    HT* __restrict__ hidden) {
  __shared__ bf16_t As[BM][BK]; // 128 x 128 B = 16 KB
  __shared__ bf16_t Bs[BN][BK]; // 16 KB (WT is already [n][k] in global)
  int tid = threadIdx.x;
  int wave = tid >> 6;
  int lane = tid & 63;
  int bid = blockIdx.x;

  // XCD-aware remap (XCD = bid % 8 round-robin). R5 verified: FETCH
  // 530 -> 115 MB (ideal 130). Keep.
  int xcd = bid & 7;
  int q = bid >> 3;
  int m0 = (q & 7) * BM;                 // 8 row tiles over B=1024
  int nbase = (xcd * 64 + (q >> 3)) * BN; // 512 col tiles over T*H=65536

  const bf16_t* Aptr = Xb + (size_t)m0 * L_N;
  const bf16_t* Bptr = WT + (size_t)nbase * L_N;

  // staging: lane copies 16 B; one gload_lds covers 8 rows x 128 B; each
  // wave stages rows [wave*32, wave*32+32) in 4 instrs (A) + 4 (B).
  int srow = lane >> 3;      // 0..7 within instr
  int scol = lane & 7;       // 16-B chunk within row
  size_t soff = (size_t)(wave * 32 + srow) * L_N + scol * 8;

  f32x4_t acc[4][4];
  f32x4_t zero = {0.f, 0.f, 0.f, 0.f};
#pragma unroll
  for (int i = 0; i < 4; i++)
#pragma unroll
    for (int j = 0; j < 4; j++) acc[i][j] = zero;

  int wm = wave >> 1, wn = wave & 1;
  int fr = lane & 15;
  int fq = lane >> 4;

  for (int k0 = 0; k0 < L_N; k0 += BK) {
    const bf16_t* ga = Aptr + soff + k0;
    const bf16_t* gb = Bptr + soff + k0;
#pragma unroll
    for (int i = 0; i < 4; i++) {
      async_load16(ga + (size_t)i * 8 * L_N, &As[wave * 32 + i * 8][0]);
      async_load16(gb + (size_t)i * 8 * L_N, &Bs[wave * 32 + i * 8][0]);
    }
    __syncthreads();
#pragma unroll
    for (int ks = 0; ks < 2; ks++) {
      bf16x8_t af[4], bfv[4];
#pragma unroll
      for (int i = 0; i < 4; i++)
        af[i] = *(const bf16x8_t*)&As[wm * 64 + i * 16 + fr][ks * 32 + fq * 8];
#pragma unroll
      for (int j = 0; j < 4; j++)
        bfv[j] = *(const bf16x8_t*)&Bs[wn * 64 + j * 16 + fr][ks * 32 + fq * 8];
#pragma unroll
      for (int i = 0; i < 4; i++)
#pragma unroll
        for (int j = 0; j < 4; j++)
          acc[i][j] =
              __builtin_amdgcn_mfma_f32_16x16x32_bf16(af[i], bfv[j], acc[i][j], 0, 0, 0);
    }
    __syncthreads();
  }
  // SQ_LDS_BANK_CONFLICT on fragment reads: hidden under the 2-phase
  // stage+barrier critical path (guide m230/m252: T2 null at 2ph). Ignore.

  // C/D layout: col = lane&15, row = (lane>>4)*4 + r  [verified m89/m91]
#pragma unroll
  for (int i = 0; i < 4; i++) {
    int gm = m0 + wm * 64 + i * 16 + fq * 4;
#pragma unroll
    for (int j = 0; j < 4; j++) {
      int gn = nbase + wn * 64 + j * 16 + fr;
      HT* outp = hidden + (size_t)gm * NCOL + gn;
#pragma unroll
      for (int r = 0; r < 4; r++) outp[(size_t)r * NCOL] = (HT)acc[i][j][r];
    }
  }
}

// ---------------- helpers shared by the tail kernels ----------------

__device__ __forceinline__ float wave_reduce_sum(float v) {
#pragma unroll
  for (int off = 32; off > 0; off >>= 1) v += __shfl_xor(v, off);
  return v;
}

__device__ __forceinline__ int lanes_below(unsigned long long m) {
  return (int)__builtin_amdgcn_mbcnt_hi((unsigned)(m >> 32),
                                        __builtin_amdgcn_mbcnt_lo((unsigned)m, 0u));
}

// ---------------- kernel A: top-64 select + sort -> g[B,T,64] f32 ----------------
// 16-bit keys (R7): bf16 hidden -> threshold search over 16 bits.
// (256,3) = 85-VGPR budget; need ~60.
__global__ __launch_bounds__(256, 3) void topk_select_kernel(
    const bf16_t* __restrict__ hidden, float* __restrict__ g_out) {
  __shared__ unsigned slots[4][K_TOP];
  int t = blockIdx.y;
  int wave = threadIdx.x >> 6;
  int lane = threadIdx.x & 63;
  int b = blockIdx.x * 4 + wave;

  unsigned key[32];
  {
    const u16x8* r8 = (const u16x8*)(hidden + (size_t)b * NCOL + (size_t)t * H_N);
#pragma unroll
    for (int h = 0; h < 2; h++) {
      u16x8 v[2];
#pragma unroll
      for (int qq = 0; qq < 2; qq++) v[qq] = r8[lane + 64 * (h * 2 + qq)];
#pragma unroll
      for (int qq = 0; qq < 2; qq++)
#pragma unroll
        for (int j = 0; j < 8; j++) {
          unsigned u = v[qq][j];
          key[(h * 2 + qq) * 8 + j] = u ^ ((u >> 15) ? 0xFFFFu : 0x8000u);
        }
    }
  }

  // exact 64th-largest key: largest thr with count(key >= thr) >= 64
  unsigned thr = 0;
  for (int bit = 15; bit >= 0; --bit) {
    unsigned cand = thr | (1u << bit);
    int c = 0;
#pragma unroll
    for (int i = 0; i < 32; i++) c += (int)__popcll(__ballot(key[i] >= cand));
    if (c >= K_TOP) thr = cand; // wave-uniform
  }

  // compaction via ballot prefix (no atomics, wave-local LDS only)
  int base = 0;
#pragma unroll
  for (int i = 0; i < 32; i++) {
    bool p = key[i] > thr;
    unsigned long long m = __ballot(p);
    if (p) slots[wave][base + lanes_below(m)] = key[i];
    base += (int)__popcll(m);
  }
#pragma unroll
  for (int i = 0; i < 32; i++) {
    bool p = key[i] == thr;
    unsigned long long m = __ballot(p);
    if (p) {
      int pos = base + lanes_below(m);
      if (pos < K_TOP) slots[wave][pos] = key[i];
    }
    base += (int)__popcll(m);
  }

  // 64-lane register bitonic sort, descending (16-bit keys in u32)
  unsigned g = slots[wave][lane];
#pragma unroll
  for (int k = 2; k <= 64; k <<= 1) {
#pragma unroll
    for (int j = k >> 1; j > 0; j >>= 1) {
      unsigned other = (unsigned)__shfl_xor((int)g, j);
      bool keep_max = (((lane & k) == 0) != ((lane & j) != 0));
      unsigned mx = g > other ? g : other;
      unsigned mn = g > other ? other : g;
      g = keep_max ? mx : mn;
    }
  }
  // key16 -> bf16 bits -> f32
  unsigned u = g ^ ((g >> 15) ? 0x8000u : 0xFFFFu);
  g_out[((size_t)b * T_N + t) * K_TOP + lane] = __uint_as_float(u << 16);
}

// ---------------- kernel B: dense + GELU + LN from g ----------------

__device__ __forceinline__ void gelu_ln_store4(f32x4_t y,
                                               const float* __restrict__ gm,
                                               const float* __restrict__ bt,
                                               float* __restrict__ op, int lane) {
  const float is2 = 0.70710678118654752f;
#pragma unroll
  for (int j = 0; j < 4; j++) y[j] = 0.5f * y[j] * (1.f + erff(y[j] * is2));
  float mean = wave_reduce_sum(y[0] + y[1] + y[2] + y[3]) * (1.f / 256.f);
  f32x4_t d;
#pragma unroll
  for (int j = 0; j < 4; j++) d[j] = y[j] - mean;
  float var = wave_reduce_sum(d[0] * d[0] + d[1] * d[1] + d[2] * d[2] + d[3] * d[3]) *
              (1.f / 256.f);
  float rstd = rsqrtf(var + 1e-6f);
  f32x4_t gmv = *(const f32x4_t*)(gm + 4 * lane);
  f32x4_t btv = *(const f32x4_t*)(bt + 4 * lane);
  f32x4_t o;
#pragma unroll
  for (int j = 0; j < 4; j++) o[j] = d[j] * rstd * gmv[j] + btv[j];
  *(f32x4_t*)(op + 4 * lane) = o;
}

// R8: 32 rows/block (was 16) -> halves block count and the per-block
// 64 KB Wd stage+sync prologues. a[8]/gr[8] statically unrolled (rule #20);
// load window per c-iter: 8 uniform ds + 4 wlds b128 -> bounded, no spill.
// LDS 72 KB -> 2 blocks/CU.
__global__ __launch_bounds__(256, 2) void dense_tail_kernel(
    const float* __restrict__ g_in, const float* __restrict__ Wd,
    const float* __restrict__ bd, const float* __restrict__ gamma,
    const float* __restrict__ beta, float* __restrict__ out) {
  __shared__ f32x4_t wlds4[K_TOP * O_N / 4]; // 64 KB, layout [k][64 float4]
  __shared__ f32x4_t glds4[4][8][K_TOP / 4]; // 8 KB: [wave][row][k-chunk]
  int t = blockIdx.y;
  int wave = threadIdx.x >> 6;
  int lane = threadIdx.x & 63;
  int b0 = blockIdx.x * 32 + wave; // rows b0 + 4j, j=0..7

  // cooperative Wd stage: 4096 float4, 16 per thread (straight copy)
  {
    const f32x4_t* src = (const f32x4_t*)(Wd + (size_t)t * K_TOP * O_N);
#pragma unroll
    for (int i = 0; i < 16; i++)
      wlds4[threadIdx.x + 256 * i] = src[threadIdx.x + 256 * i];
  }

  // stage this wave's 8 g rows into LDS (lane k holds g[k])
#pragma unroll
  for (int j = 0; j < 8; j++) {
    float* gj = (float*)&glds4[wave][j][0];
    gj[lane] = g_in[((size_t)(b0 + 4 * j) * T_N + t) * K_TOP + lane];
  }

  const float* bdt = bd + t * O_N;
  f32x4_t bb = *(const f32x4_t*)(bdt + 4 * lane);
  f32x4_t a[8];
#pragma unroll
  for (int j = 0; j < 8; j++) a[j] = bb;

  __syncthreads();

#pragma unroll 1
  for (int c = 0; c < K_TOP / 4; c++) {
    f32x4_t gr[8];
#pragma unroll
    for (int j = 0; j < 8; j++) gr[j] = glds4[wave][j][c]; // uniform -> broadcast
#pragma unroll
    for (int kk = 0; kk < 4; kk++) {
      f32x4_t w = wlds4[(c * 4 + kk) * 64 + lane];
#pragma unroll
      for (int j = 0; j < 8; j++)
#pragma unroll
        for (int qq = 0; qq < 4; qq++) a[j][qq] = fmaf(gr[j][kk], w[qq], a[j][qq]);
    }
  }

  const float* gm = gamma + t * O_N;
  const float* bt = beta + t * O_N;
#pragma unroll
  for (int j = 0; j < 8; j++)
    gelu_ln_store4(a[j], gm, bt, out + ((size_t)(b0 + 4 * j) * T_N + t) * O_N, lane);
}

// ---------------- launch ----------------
extern "C" void kernel_launch(void* const* d_in, const int* in_sizes, int n_in,
                              void* d_out, int out_size, void* d_ws, size_t ws_size,
                              hipStream_t stream) {
  const float* x = (const float*)d_in[0];
  const float* Wt = (const float*)d_in[1];
  const float* Wd = (const float*)d_in[2];
  const float* bd = (const float*)d_in[3];
  const float* gamma = (const float*)d_in[4];
  const float* beta = (const float*)d_in[5];
  float* out = (float*)d_out;

  char* ws = (char*)d_ws;
  size_t sz_wt = (size_t)T_N * H_N * L_N * 2; // 128 MB
  size_t sz_x = (size_t)B_N * L_N * 2;        // 2 MB
  size_t off_h = sz_wt + sz_x;
  size_t sz_h_b16 = (size_t)B_N * NCOL * 2;   // 128 MB
  size_t sz_g = (size_t)B_N * T_N * K_TOP * 4; // 8 MB

  bf16_t* WTb = (bf16_t*)ws;
  bf16_t* Xb = (bf16_t*)(ws + sz_wt);

  cvt_x_kernel<<<B_N * L_N / 1024, 256, 0, stream>>>(x, Xb);
  cvt_w_kernel<<<dim3(H_N / 64, L_N / 64, T_N), 256, 0, stream>>>(Wt, WTb);

  bf16_t* hidden = (bf16_t*)(ws + off_h);
  float* gbuf = (ws_size >= off_h + sz_h_b16 + sz_g)
                    ? (float*)(ws + off_h + sz_h_b16)
                    : (float*)ws; // overlap WT (dead after gemm1)
  gemm1_kernel<bf16_t><<<4096, 256, 0, stream>>>(Xb, WTb, hidden);
  topk_select_kernel<<<dim3(B_N / 4, T_N), 256, 0, stream>>>(hidden, gbuf);
  dense_tail_kernel<<<dim3(B_N / 32, T_N), 256, 0, stream>>>(gbuf, Wd, bd, gamma,
                                                             beta, out);
}